// Round 7
// baseline (164.446 us; speedup 1.0000x reference)
//
#include <hip/hip_runtime.h>

// Problem constants (match reference)
#define T_TICKS 128
#define NCPAIR  10000
#define NCROSS  30000
#define E_EDGES 120000
#define TG      8              // ticks per thread in k_gat
#define NTG     (T_TICKS / TG) // 16 tick groups
#define NBLK_N  ((NCROSS + 255) / 256)  // 118 blocks over nodes
#define DEGBINS 64
#define EPB     ((E_EDGES + NBLK_N - 1) / NBLK_N)  // 1017 edges per hist block

// ---------------- CSR build (graph is tick-independent) ----------------

// 118 blocks x 256. Per block: local scan of counts, block base via one
// global atomicAdd (CSR bucket order is irrelevant), block-LOCAL descending
// degree counting-sort -> packed (beg,deg,node) records. Keeping the
// permutation inside each 256-node window lets k_gat un-permute via LDS.
__global__ void k_apply(const int* __restrict__ counts, int* __restrict__ gbase,
                        int* __restrict__ cursor, int4* __restrict__ begdegn) {
    __shared__ int s[256];
    __shared__ int bins[DEGBINS];
    __shared__ int binoff[DEGBINS];
    __shared__ int sbase;
    const int tid = threadIdx.x;
    const int n = blockIdx.x * 256 + tid;
    const int c = (n < NCROSS) ? counts[n] : 0;
    s[tid] = c;
    if (tid < DEGBINS) bins[tid] = 0;
    __syncthreads();
    for (int off = 1; off < 256; off <<= 1) {
        int v = (tid >= off) ? s[tid - off] : 0;
        __syncthreads();
        s[tid] += v;
        __syncthreads();
    }
    if (tid == 0) sbase = atomicAdd(gbase, s[255]);
    int bin = 0, lp = 0;
    if (n < NCROSS) {
        bin = c < DEGBINS ? c : DEGBINS - 1;
        lp = atomicAdd(&bins[bin], 1);
    }
    __syncthreads();
    if (tid == 0) {
        int run = 0;
        for (int d = DEGBINS - 1; d >= 0; d--) { binoff[d] = run; run += bins[d]; }
    }
    __syncthreads();
    if (n < NCROSS) {
        const int beg = sbase + s[tid] - c;
        cursor[n] = beg;
        const int rank = binoff[bin] + lp;
        begdegn[blockIdx.x * 256 + rank] = make_int4(beg, c, n, 0);
    }
}

__global__ void k_scatter(const int* __restrict__ src, const int* __restrict__ dst,
                          int* __restrict__ cursor, int* __restrict__ sorted_src) {
    int i = blockIdx.x * blockDim.x + threadIdx.x;
    if (i < E_EDGES) {
        int p = atomicAdd(&cursor[dst[i]], 1);
        sorted_src[p] = src[i];
    }
}

// ---------------- per-node affine coefficients ----------------
// s(n,t) = sB + xA[chA][t]*sA1 + xB[chB][t]*sB1 + t*sT   (same for d, p)
// where s = h.a_src, d = h.a_dst, p = h.Wm, h = nodes @ W_gat + b_gat.
// crec[n] = 4 float4s (64 B): (sB,sA1,sB1,sT) (pB,pA1,pB1,pT) (dB,dA1,dB1,dT)
// (chA,chB as int bits, -, -). Total table: 1.92 MB -> L2-resident per XCD.
// Edge histogram fused in (saves a dispatch).

__global__ void k_coef(const float* __restrict__ x,
                       const int* __restrict__ c0, const int* __restrict__ c1,
                       const int* __restrict__ c2,
                       const int* __restrict__ g01, const int* __restrict__ g12,
                       const int* __restrict__ g20,
                       const float* __restrict__ r01,
                       const float* __restrict__ r12,
                       const float* __restrict__ r20,
                       const float* __restrict__ Wg,
                       const float* __restrict__ bg,
                       const float* __restrict__ as_,
                       const float* __restrict__ ad_,
                       const float* __restrict__ Wm,
                       const int* __restrict__ e_dst, int* __restrict__ counts,
                       float4* __restrict__ crec) {
    const int tid = threadIdx.x;
    // fused edge histogram
    {
        const int lo = blockIdx.x * EPB;
        const int hi = min(lo + EPB, E_EDGES);
        for (int i = lo + tid; i < hi; i += 256) atomicAdd(&counts[e_dst[i]], 1);
    }
    const int n = blockIdx.x * 256 + tid;
    if (n >= NCROSS) return;

    int iA, iB, m;
    float pA, pB;
    const int* cA;
    const int* cB;
    const float* ray;
    if (n < NCPAIR) {
        m = n; cA = c0; cB = c1; pA = 0.f; pB = 1.f; ray = r01;
        iA = g01[2 * m]; iB = g01[2 * m + 1];
    } else if (n < 2 * NCPAIR) {
        m = n - NCPAIR; cA = c1; cB = c2; pA = 1.f; pB = 2.f; ray = r12;
        iA = g12[2 * m]; iB = g12[2 * m + 1];
    } else {
        m = n - 2 * NCPAIR; cA = c2; cB = c0; pA = 2.f; pB = 0.f; ray = r20;
        iA = g20[2 * m]; iB = g20[2 * m + 1];
    }
    const int chA = cA[iA];
    const int chB = cB[iB];
    const float rx = ray[2 * m];
    const float ry = ray[2 * m + 1];

    // tick-static part of nodes @ W_gat + b (excludes sigA, sigB, tick rows)
    float base[4];
#pragma unroll
    for (int c = 0; c < 4; c++) {
        base[c] = bg[c]
                + (float)iA  * Wg[1 * 4 + c] + (float)chA * Wg[2 * 4 + c]
                + pA         * Wg[4 * 4 + c]
                + (float)iB  * Wg[6 * 4 + c] + (float)chB * Wg[7 * 4 + c]
                + pB         * Wg[9 * 4 + c]
                + rx         * Wg[10 * 4 + c] + ry * Wg[11 * 4 + c];
    }
    float sB = 0, dB = 0, pBs = 0;
    float sA1 = 0, dA1 = 0, pA1 = 0;
    float sB1 = 0, dB1 = 0, pB1 = 0;
    float sT = 0, dT = 0, pT = 0;
#pragma unroll
    for (int c = 0; c < 4; c++) {
        const float va = as_[c], vd = ad_[c], vm = Wm[c];
        sB  += base[c] * va;  dB  += base[c] * vd;  pBs += base[c] * vm;
        sA1 += Wg[c] * va;    dA1 += Wg[c] * vd;    pA1 += Wg[c] * vm;
        sB1 += Wg[5*4+c]*va;  dB1 += Wg[5*4+c]*vd;  pB1 += Wg[5*4+c]*vm;
        sT  += Wg[12*4+c]*va; dT  += Wg[12*4+c]*vd; pT  += Wg[12*4+c]*vm;
    }
    crec[(size_t)n * 4 + 0] = make_float4(sB, sA1, sB1, sT);
    crec[(size_t)n * 4 + 1] = make_float4(pBs, pA1, pB1, pT);
    crec[(size_t)n * 4 + 2] = make_float4(dB, dA1, dB1, dT);
    crec[(size_t)n * 4 + 3] = make_float4(__int_as_float(chA),
                                          __int_as_float(chB), 0.f, 0.f);
}

// ---------------- fused GAT aggregation + MLP + sigmoid ----------------
// one thread = (node, 8 ticks); single-pass online softmax (single exp).
// s,p of each src evaluated on the fly from its 64-B coeff record + x rows
// (both L2-resident) -> no big intermediate slab.

__device__ __forceinline__ void upd(float& mx, float& den, float& p,
                                    const float e, const float pj) {
    const float dif = e - mx;
    const float ex = __expf(-fabsf(dif));
    const bool g = dif > 0.f;
    const float scale = g ? ex : 1.f;
    const float w = g ? 1.f : ex;
    mx = g ? e : mx;
    den = fmaf(den, scale, w);
    p = fmaf(p, scale, w * pj);
}

__device__ __forceinline__ void edge_upd(const float4* __restrict__ crec,
                                         const float* __restrict__ x,
                                         const int src, const int t0,
                                         const float* dd, float* mx,
                                         float* den, float* pa) {
    const float4 ca = crec[(size_t)src * 4 + 0];
    const float4 cp = crec[(size_t)src * 4 + 1];
    const float4 cq = crec[(size_t)src * 4 + 3];
    const int chA = __float_as_int(cq.x);
    const int chB = __float_as_int(cq.y);
    const float4 xa0 = *(const float4*)(x + chA * T_TICKS + t0);
    const float4 xa1 = *(const float4*)(x + chA * T_TICKS + t0 + 4);
    const float4 xb0 = *(const float4*)(x + chB * T_TICKS + t0);
    const float4 xb1 = *(const float4*)(x + chB * T_TICKS + t0 + 4);
    const float sa[8] = {xa0.x, xa0.y, xa0.z, xa0.w, xa1.x, xa1.y, xa1.z, xa1.w};
    const float sb[8] = {xb0.x, xb0.y, xb0.z, xb0.w, xb1.x, xb1.y, xb1.z, xb1.w};
    float sbase = fmaf((float)t0, ca.w, ca.x);
    float pbase = fmaf((float)t0, cp.w, cp.x);
#pragma unroll
    for (int k = 0; k < TG; k++) {
        float e = fmaf(sa[k], ca.y, fmaf(sb[k], ca.z, sbase)) + dd[k];
        e = fmaxf(e, 0.2f * e);
        const float pj = fmaf(sa[k], cp.y, fmaf(sb[k], cp.z, pbase));
        upd(mx[k], den[k], pa[k], e, pj);
        sbase += ca.w;
        pbase += cp.w;
    }
}

__global__ void k_gat(const float4* __restrict__ crec,
                      const float* __restrict__ x,
                      const int4* __restrict__ begdegn,
                      const int* __restrict__ ssrc,
                      const float* __restrict__ bm,
                      float* __restrict__ out) {
    const int nb = blockIdx.x;
    const int tg = blockIdx.y;
    const int t0 = tg * TG;
    const int bbase = nb * 256;
    const int tid = threadIdx.x;
    const int idx = bbase + tid;

    __shared__ float lres[TG][257];

    if (idx < NCROSS) {
        const int4 bd = begdegn[idx];
        const int beg = bd.x, deg = bd.y, n = bd.z;
        const int localn = n & 255;

        // own-node d(t) from coeffs
        float dd[TG];
        {
            const float4 cd = crec[(size_t)n * 4 + 2];
            const float4 cq = crec[(size_t)n * 4 + 3];
            const int chA = __float_as_int(cq.x);
            const int chB = __float_as_int(cq.y);
            const float4 xa0 = *(const float4*)(x + chA * T_TICKS + t0);
            const float4 xa1 = *(const float4*)(x + chA * T_TICKS + t0 + 4);
            const float4 xb0 = *(const float4*)(x + chB * T_TICKS + t0);
            const float4 xb1 = *(const float4*)(x + chB * T_TICKS + t0 + 4);
            const float sa[8] = {xa0.x, xa0.y, xa0.z, xa0.w,
                                 xa1.x, xa1.y, xa1.z, xa1.w};
            const float sb[8] = {xb0.x, xb0.y, xb0.z, xb0.w,
                                 xb1.x, xb1.y, xb1.z, xb1.w};
            float dbase = fmaf((float)t0, cd.w, cd.x);
#pragma unroll
            for (int k = 0; k < TG; k++) {
                dd[k] = fmaf(sa[k], cd.y, fmaf(sb[k], cd.z, dbase));
                dbase += cd.w;
            }
        }

        float mx[TG], den[TG], pa[TG];
#pragma unroll
        for (int k = 0; k < TG; k++) { mx[k] = -INFINITY; den[k] = 0.f; pa[k] = 0.f; }

        int j = beg;
        const int e2 = beg + (deg & ~1);
        for (; j < e2; j += 2) {
            const int s0 = ssrc[j];
            const int s1 = ssrc[j + 1];
            edge_upd(crec, x, s0, t0, dd, mx, den, pa);
            edge_upd(crec, x, s1, t0, dd, mx, den, pa);
        }
        if (deg & 1) edge_upd(crec, x, ssrc[j], t0, dd, mx, den, pa);

        const float bb = bm[0];
#pragma unroll
        for (int k = 0; k < TG; k++) {
            const float logit = pa[k] / (den[k] + 1e-9f) + bb;
            lres[k][localn] = 1.f / (1.f + __expf(-logit));
        }
    }
    __syncthreads();
    if (idx < NCROSS) {
#pragma unroll
        for (int k = 0; k < TG; k++) {
            out[(size_t)(t0 + k) * NCROSS + bbase + tid] = lres[k][tid];
        }
    }
}

// ---------------- launch ----------------

extern "C" void kernel_launch(void* const* d_in, const int* in_sizes, int n_in,
                              void* d_out, int out_size, void* d_ws, size_t ws_size,
                              hipStream_t stream) {
    const float* x   = (const float*)d_in[0];
    const int* c0  = (const int*)d_in[1];
    const int* c1  = (const int*)d_in[2];
    const int* c2  = (const int*)d_in[3];
    const int* g01 = (const int*)d_in[4];
    const int* g12 = (const int*)d_in[5];
    const int* g20 = (const int*)d_in[6];
    const float* r01 = (const float*)d_in[7];
    const float* r12 = (const float*)d_in[8];
    const float* r20 = (const float*)d_in[9];
    const int* edges = (const int*)d_in[10];          // [2, E]
    const float* Wg  = (const float*)d_in[11];
    const float* as_ = (const float*)d_in[12];
    const float* ad_ = (const float*)d_in[13];
    const float* bg  = (const float*)d_in[14];
    const float* Wm  = (const float*)d_in[15];
    const float* bm  = (const float*)d_in[16];
    float* out = (float*)d_out;

    const int* e_src = edges;
    const int* e_dst = edges + E_EDGES;

    // workspace layout (counts+gbase contiguous for single memset)
    char* ws = (char*)d_ws;
    size_t off = 0;
    int* counts     = (int*)(ws + off); off += NCROSS * sizeof(int);
    int* gbase      = (int*)(ws + off); off += sizeof(int);
    int* cursor     = (int*)(ws + off); off += NCROSS * sizeof(int);
    int* sorted_src = (int*)(ws + off); off += E_EDGES * sizeof(int);
    off = (off + 15) & ~(size_t)15;
    int4* begdegn   = (int4*)(ws + off); off += (size_t)NBLK_N * 256 * sizeof(int4);
    off = (off + 63) & ~(size_t)63;
    float4* crec    = (float4*)(ws + off); off += (size_t)NCROSS * 64;  // 1.92 MB
    (void)ws_size; (void)n_in; (void)in_sizes; (void)out_size;

    hipMemsetAsync(counts, 0, (NCROSS + 1) * sizeof(int), stream);

    k_coef<<<NBLK_N, 256, 0, stream>>>(x, c0, c1, c2, g01, g12, g20,
                                       r01, r12, r20, Wg, bg, as_, ad_, Wm,
                                       e_dst, counts, crec);
    k_apply<<<NBLK_N, 256, 0, stream>>>(counts, gbase, cursor, begdegn);
    const int eb = (E_EDGES + 255) / 256;
    k_scatter<<<eb, 256, 0, stream>>>(e_src, e_dst, cursor, sorted_src);
    dim3 gridG(NBLK_N, NTG);
    k_gat<<<gridG, 256, 0, stream>>>(crec, x, begdegn, sorted_src, bm, out);
}